// Round 5
// baseline (82.919 us; speedup 1.0000x reference)
//
#include <hip/hip_runtime.h>
#include <hip/hip_bf16.h>

// Quantizer (VQ-VAE): inputs [32,2048,256] f32, embed [1024,256] f32.
// out = (quantized [32,2048,256] f32, latent_loss scalar f32) concatenated.
//
// Round-4 structure: 64-row tiles, 1024 blocks, 4 blocks/CU target
// (LDS 34 KiB, VGPR <= 128 via __launch_bounds__(256,4)) so that block
// phase bursts (HBM read / MFMA loop / HBM write) overlap ACROSS blocks.
//
//   prep_kernel : embed -> bf16 PRE-SWIZZLED copy (ws) + cneg[k] = -0.5*||e_k||^2
//   vq_kernel   : X->regs, Es 32-code chunks double-buffered via global_load_lds,
//                 bf16-MFMA argmin, fused q = ew[code] write + algebraic loss
//   loss_kernel : final reduce -> 1.25 * [sum(x^2) - 2*sum(sv_win)] / (N*D)

#define DIM     256
#define M_ROWS  65536
#define NCODES  1024
#define ROWS    64            // rows per block
#define CHUNK   32            // codes per Es chunk (16 KiB)
#define NCHUNK  32

using bf16x8  = __attribute__((ext_vector_type(8))) short;
using f32x4   = __attribute__((ext_vector_type(4))) float;
using short4v = __attribute__((ext_vector_type(4))) short;

__device__ inline short f2bf(float f) {
  union { __hip_bfloat16 h; short s; } u;
  u.h = __float2bfloat16(f);   // RTNE
  return u.s;
}

__device__ inline void gload_lds16(const short* g, short* l) {
  __builtin_amdgcn_global_load_lds(
      (const __attribute__((address_space(1))) void*)g,
      (__attribute__((address_space(3))) void*)l, 16, 0, 0);
}

// ---------------------------------------------------------------- prep
// ebf layout: row-major [code][256] bf16; 16B units within each row permuted
// u -> u ^ (code & 15). vq stages rows linearly into LDS (global_load_lds),
// reads with the same XOR -> conflict-free ds_read_b128.
__global__ __launch_bounds__(64) void prep_kernel(const float* __restrict__ ew,
                                                  short* __restrict__ ebf,
                                                  float* __restrict__ cneg) {
  const int code = blockIdx.x;
  const int t    = threadIdx.x;
  f32x4 v = *((const f32x4*)(ew + (size_t)code * DIM) + t);
  short4v o;
  o.x = f2bf(v[0]); o.y = f2bf(v[1]); o.z = f2bf(v[2]); o.w = f2bf(v[3]);
  int u = t >> 1, h = t & 1;
  int off = code * 256 + ((u ^ (code & 15)) << 3) + h * 4;
  *(short4v*)(ebf + off) = o;
  float ss = v[0] * v[0] + v[1] * v[1] + v[2] * v[2] + v[3] * v[3];
#pragma unroll
  for (int off2 = 32; off2 > 0; off2 >>= 1) ss += __shfl_xor(ss, off2, 64);
  if (t == 0) cneg[code] = -0.5f * ss;
}

// ---------------------------------------------------------------- fused vq
__global__ __launch_bounds__(256, 4) void vq_kernel(const float* __restrict__ x,
                                                    const short* __restrict__ ebf,
                                                    const float* __restrict__ cneg,
                                                    const float* __restrict__ ew,
                                                    float* __restrict__ qout,
                                                    float* __restrict__ partials) {
  __shared__ short buf[2][CHUNK * 256];   // 2 x 16 KiB: Es dbuf; buf[1] also X-staging
  __shared__ float cands[2][ROWS];
  __shared__ int   codes[ROWS];
  __shared__ float red[256];

  const int tid  = threadIdx.x;
  const int lane = tid & 63;
  const int wid  = tid >> 6;
  const int wr   = wid >> 1;           // wave row group (0..1), 32 rows each
  const int wc   = wid & 1;            // wave col group (0..1), 16 codes/chunk each
  const int l15  = lane & 15;
  const int lhi  = lane >> 4;          // 0..3
  const int row0 = blockIdx.x * ROWS;

  // ---- prefetch Es chunk 0 into buf[0] (overlaps the X read burst) ----
#pragma unroll
  for (int it = 0; it < 4; ++it)
    gload_lds16(ebf + it * 2048 + tid * 8, &buf[0][it * 2048 + tid * 8]);

  // ---- stage X in two 32-row halves through buf[1]; frags -> registers ----
  float x2a = 0.0f;
  bf16x8 a[2][8];
  for (int h = 0; h < 2; ++h) {
#pragma unroll
    for (int st = 0; st < 4; ++st) {
      int f8 = st * 256 + tid;         // 8-float unit id within half
      int r  = f8 >> 5;                // local row 0..31
      int u  = f8 & 31;
      const float* src = x + (size_t)(row0 + h * 32 + r) * DIM + u * 8;
      f32x4 v0 = __builtin_nontemporal_load((const f32x4*)src);
      f32x4 v1 = __builtin_nontemporal_load(((const f32x4*)src) + 1);
      x2a += v0[0] * v0[0] + v0[1] * v0[1] + v0[2] * v0[2] + v0[3] * v0[3]
           + v1[0] * v1[0] + v1[1] * v1[1] + v1[2] * v1[2] + v1[3] * v1[3];
      union { bf16x8 v; short s[8]; } pk;
      pk.s[0] = f2bf(v0[0]); pk.s[1] = f2bf(v0[1]); pk.s[2] = f2bf(v0[2]); pk.s[3] = f2bf(v0[3]);
      pk.s[4] = f2bf(v1[0]); pk.s[5] = f2bf(v1[1]); pk.s[6] = f2bf(v1[2]); pk.s[7] = f2bf(v1[3]);
      *(bf16x8*)&buf[1][r * 256 + ((u ^ (r & 15)) << 3)] = pk.v;
    }
    __syncthreads();
    if (wr == h) {
#pragma unroll
      for (int mi = 0; mi < 2; ++mi)
#pragma unroll
        for (int kk = 0; kk < 8; ++kk) {
          int rl = mi * 16 + l15;      // local row; rl & 15 == l15
          a[mi][kk] = *(const bf16x8*)&buf[1][rl * 256 + (((kk * 4 + lhi) ^ l15) << 3)];
        }
    }
    __syncthreads();
  }

  float bk[2][4];
#pragma unroll
  for (int i = 0; i < 2; ++i)
#pragma unroll
    for (int r = 0; r < 4; ++r) bk[i][r] = -__builtin_inff();

  const int cl = wc * 16 + l15;        // code-lane within chunk; cl & 15 == l15

  // ---- chunk loop: prefetch c+1, compute c, one barrier per chunk ----
  for (int c = 0; c < NCHUNK; ++c) {
    const int cur = c & 1;
    if (c + 1 < NCHUNK) {
      const short* gb = ebf + (c + 1) * (CHUNK * 256);
#pragma unroll
      for (int it = 0; it < 4; ++it)
        gload_lds16(gb + it * 2048 + tid * 8, &buf[cur ^ 1][it * 2048 + tid * 8]);
    }

    int code = c * CHUNK + cl;
    float    ct = cneg[code];
    unsigned tr = (unsigned)(1023 - code);

    f32x4 acc0 = f32x4{0.f, 0.f, 0.f, 0.f};
    f32x4 acc1 = f32x4{0.f, 0.f, 0.f, 0.f};
#pragma unroll
    for (int kk = 0; kk < 8; ++kk) {
      bf16x8 b = *(const bf16x8*)&buf[cur][cl * 256 + (((kk * 4 + lhi) ^ l15) << 3)];
      acc0 = __builtin_amdgcn_mfma_f32_16x16x32_bf16(a[0][kk], b, acc0, 0, 0, 0);
      acc1 = __builtin_amdgcn_mfma_f32_16x16x32_bf16(a[1][kk], b, acc1, 0, 0, 0);
    }

    // fold into running best keys: key = (sv & ~1023) | (1023-code)
#pragma unroll
    for (int r = 0; r < 4; ++r) {
      float sv0 = acc0[r] + ct;
      bk[0][r] = fmaxf(bk[0][r], __uint_as_float((__float_as_uint(sv0) & 0xFFFFFC00u) | tr));
      float sv1 = acc1[r] + ct;
      bk[1][r] = fmaxf(bk[1][r], __uint_as_float((__float_as_uint(sv1) & 0xFFFFFC00u) | tr));
    }

    __syncthreads();   // drains prefetch (c+1 ready) + frees buf[cur] readers
  }

  // ---- reduce across 16 code-lanes, resolve per-row winner ----
#pragma unroll
  for (int mi = 0; mi < 2; ++mi)
#pragma unroll
    for (int r = 0; r < 4; ++r) {
      float v = bk[mi][r];
#pragma unroll
      for (int off = 1; off < 16; off <<= 1) v = fmaxf(v, __shfl_xor(v, off, 64));
      if (l15 == 0) cands[wc][wr * 32 + mi * 16 + lhi * 4 + r] = v;
    }
  __syncthreads();

  float sv = 0.0f;
  if (tid < ROWS) {
    float k = fmaxf(cands[0][tid], cands[1][tid]);
    unsigned ku = __float_as_uint(k);
    codes[tid] = 1023 - (int)(ku & 1023u);
    sv = __uint_as_float(ku & 0xFFFFFC00u);
  }
  red[tid] = x2a - 2.0f * sv;          // block partial: sum x^2 - 2*sum sv
  __syncthreads();
  for (int s = 128; s > 0; s >>= 1) {
    if (tid < s) red[tid] += red[tid + s];
    __syncthreads();
  }
  if (tid == 0) partials[blockIdx.x] = red[0];

  // ---- fused gather: q = ew[code], exact fp32, nontemporal streamed write ----
#pragma unroll 8
  for (int j = 0; j < 16; ++j) {
    int f4 = j * 256 + tid;            // float4 id within the 64x256 tile
    int rw = f4 >> 6;
    int c4 = f4 & 63;
    int code = codes[rw];
    f32x4 qv = *((const f32x4*)(ew + (size_t)code * DIM) + c4);
    __builtin_nontemporal_store(qv, ((f32x4*)(qout + (size_t)(row0 + rw) * DIM)) + c4);
  }
}

// ---------------------------------------------------------------- final loss
__global__ __launch_bounds__(256) void loss_kernel(const float* __restrict__ partials,
                                                   float* __restrict__ out_loss) {
  __shared__ double red[256];
  double a = 0.0;
  for (int i = threadIdx.x; i < 1024; i += 256) a += (double)partials[i];
  red[threadIdx.x] = a;
  __syncthreads();
  for (int s = 128; s > 0; s >>= 1) {
    if (threadIdx.x < s) red[threadIdx.x] += red[threadIdx.x + s];
    __syncthreads();
  }
  if (threadIdx.x == 0) out_loss[0] = (float)(1.25 * red[0] / 16777216.0);
}

// ---------------------------------------------------------------- launch
extern "C" void kernel_launch(void* const* d_in, const int* in_sizes, int n_in,
                              void* d_out, int out_size, void* d_ws, size_t ws_size,
                              hipStream_t stream) {
  const float* x  = (const float*)d_in[0];   // inputs [65536,256]
  const float* ew = (const float*)d_in[1];   // embed  [1024,256]
  float* out = (float*)d_out;

  char* ws = (char*)d_ws;
  short* ebf      = (short*)ws;                       // 512 KiB (pre-swizzled bf16)
  float* cneg     = (float*)(ws + 524288);            // 4 KiB
  float* partials = (float*)(ws + 528384);            // 4 KiB (1024 blocks)

  prep_kernel<<<NCODES, 64, 0, stream>>>(ew, ebf, cneg);
  vq_kernel<<<M_ROWS / ROWS, 256, 0, stream>>>(x, ebf, cneg, ew, out, partials);
  loss_kernel<<<1, 256, 0, stream>>>(partials, out + 16777216);
}

// Round 6
// 80.420 us; speedup vs baseline: 1.0311x; 1.0311x over previous
//
#include <hip/hip_runtime.h>
#include <hip/hip_bf16.h>

// Quantizer (VQ-VAE): inputs [32,2048,256] f32, embed [1024,256] f32.
// out = (quantized [32,2048,256] f32, latent_loss scalar f32) concatenated.
//
// Round-5 structure: DECOUPLED pipeline so each kernel has one memory
// personality (round 2-5 monolith was stuck at ~76us with all pipes <30%):
//   prep_kernel   : embed -> bf16 PRE-SWIZZLED copy + cneg[k] = -0.5*||e_k||^2
//   argmin_kernel : read x once, bf16-MFMA argmin -> codes (256 KB) + loss
//                   partials (algebraic: ||x-e||^2 = ||x||^2 - 2*sv). NO q write.
//   gather_kernel : pure streaming store: q[r] = ew[codes[r]] (1 wave = 1 row,
//                   1 KB contiguous nt-store; codebook is L2-resident).
//   loss_kernel   : final reduce -> 1.25 * [sum(x^2) - 2*sum(sv_win)] / (N*D)

#define DIM     256
#define M_ROWS  65536
#define NCODES  1024
#define ROWS    64            // rows per argmin block
#define CHUNK   32            // codes per Es chunk (16 KiB)
#define NCHUNK  32

using bf16x8  = __attribute__((ext_vector_type(8))) short;
using f32x4   = __attribute__((ext_vector_type(4))) float;
using short4v = __attribute__((ext_vector_type(4))) short;

__device__ inline short f2bf(float f) {
  union { __hip_bfloat16 h; short s; } u;
  u.h = __float2bfloat16(f);   // RTNE
  return u.s;
}

__device__ inline void gload_lds16(const short* g, short* l) {
  __builtin_amdgcn_global_load_lds(
      (const __attribute__((address_space(1))) void*)g,
      (__attribute__((address_space(3))) void*)l, 16, 0, 0);
}

// ---------------------------------------------------------------- prep
// ebf layout: row-major [code][256] bf16; 16B units within each row permuted
// u -> u ^ (code & 15). argmin stages rows linearly into LDS (global_load_lds),
// reads with the same XOR -> conflict-free ds_read_b128.
__global__ __launch_bounds__(64) void prep_kernel(const float* __restrict__ ew,
                                                  short* __restrict__ ebf,
                                                  float* __restrict__ cneg) {
  const int code = blockIdx.x;
  const int t    = threadIdx.x;
  f32x4 v = *((const f32x4*)(ew + (size_t)code * DIM) + t);
  short4v o;
  o.x = f2bf(v[0]); o.y = f2bf(v[1]); o.z = f2bf(v[2]); o.w = f2bf(v[3]);
  int u = t >> 1, h = t & 1;
  int off = code * 256 + ((u ^ (code & 15)) << 3) + h * 4;
  *(short4v*)(ebf + off) = o;
  float ss = v[0] * v[0] + v[1] * v[1] + v[2] * v[2] + v[3] * v[3];
#pragma unroll
  for (int off2 = 32; off2 > 0; off2 >>= 1) ss += __shfl_xor(ss, off2, 64);
  if (t == 0) cneg[code] = -0.5f * ss;
}

// ---------------------------------------------------------------- argmin
__global__ __launch_bounds__(256, 4) void argmin_kernel(const float* __restrict__ x,
                                                        const short* __restrict__ ebf,
                                                        const float* __restrict__ cneg,
                                                        int* __restrict__ out_codes,
                                                        float* __restrict__ partials) {
  __shared__ short buf[2][CHUNK * 256];   // 2 x 16 KiB: Es dbuf; buf[1] also X-staging
  __shared__ float cands[2][ROWS];
  __shared__ float red[256];

  const int tid  = threadIdx.x;
  const int lane = tid & 63;
  const int wid  = tid >> 6;
  const int wr   = wid >> 1;           // wave row group (0..1), 32 rows each
  const int wc   = wid & 1;            // wave col group (0..1), 16 codes/chunk each
  const int l15  = lane & 15;
  const int lhi  = lane >> 4;          // 0..3
  const int row0 = blockIdx.x * ROWS;

  // ---- prefetch Es chunk 0 into buf[0] (overlaps the X read burst) ----
#pragma unroll
  for (int it = 0; it < 4; ++it)
    gload_lds16(ebf + it * 2048 + tid * 8, &buf[0][it * 2048 + tid * 8]);

  // ---- stage X in two 32-row halves through buf[1]; frags -> registers ----
  float x2a = 0.0f;
  bf16x8 a[2][8];
  for (int h = 0; h < 2; ++h) {
#pragma unroll
    for (int st = 0; st < 4; ++st) {
      int f8 = st * 256 + tid;         // 8-float unit id within half
      int r  = f8 >> 5;                // local row 0..31
      int u  = f8 & 31;
      const float* src = x + (size_t)(row0 + h * 32 + r) * DIM + u * 8;
      f32x4 v0 = __builtin_nontemporal_load((const f32x4*)src);
      f32x4 v1 = __builtin_nontemporal_load(((const f32x4*)src) + 1);
      x2a += v0[0] * v0[0] + v0[1] * v0[1] + v0[2] * v0[2] + v0[3] * v0[3]
           + v1[0] * v1[0] + v1[1] * v1[1] + v1[2] * v1[2] + v1[3] * v1[3];
      union { bf16x8 v; short s[8]; } pk;
      pk.s[0] = f2bf(v0[0]); pk.s[1] = f2bf(v0[1]); pk.s[2] = f2bf(v0[2]); pk.s[3] = f2bf(v0[3]);
      pk.s[4] = f2bf(v1[0]); pk.s[5] = f2bf(v1[1]); pk.s[6] = f2bf(v1[2]); pk.s[7] = f2bf(v1[3]);
      *(bf16x8*)&buf[1][r * 256 + ((u ^ (r & 15)) << 3)] = pk.v;
    }
    __syncthreads();
    if (wr == h) {
#pragma unroll
      for (int mi = 0; mi < 2; ++mi)
#pragma unroll
        for (int kk = 0; kk < 8; ++kk) {
          int rl = mi * 16 + l15;      // local row; rl & 15 == l15
          a[mi][kk] = *(const bf16x8*)&buf[1][rl * 256 + (((kk * 4 + lhi) ^ l15) << 3)];
        }
    }
    __syncthreads();
  }

  float bk[2][4];
#pragma unroll
  for (int i = 0; i < 2; ++i)
#pragma unroll
    for (int r = 0; r < 4; ++r) bk[i][r] = -__builtin_inff();

  const int cl = wc * 16 + l15;        // code-lane within chunk; cl & 15 == l15

  // ---- chunk loop: prefetch c+1, compute c, one barrier per chunk ----
  for (int c = 0; c < NCHUNK; ++c) {
    const int cur = c & 1;
    if (c + 1 < NCHUNK) {
      const short* gb = ebf + (c + 1) * (CHUNK * 256);
#pragma unroll
      for (int it = 0; it < 4; ++it)
        gload_lds16(gb + it * 2048 + tid * 8, &buf[cur ^ 1][it * 2048 + tid * 8]);
    }

    int code = c * CHUNK + cl;
    float    ct = cneg[code];
    unsigned tr = (unsigned)(1023 - code);

    f32x4 acc0 = f32x4{0.f, 0.f, 0.f, 0.f};
    f32x4 acc1 = f32x4{0.f, 0.f, 0.f, 0.f};
#pragma unroll
    for (int kk = 0; kk < 8; ++kk) {
      bf16x8 b = *(const bf16x8*)&buf[cur][cl * 256 + (((kk * 4 + lhi) ^ l15) << 3)];
      acc0 = __builtin_amdgcn_mfma_f32_16x16x32_bf16(a[0][kk], b, acc0, 0, 0, 0);
      acc1 = __builtin_amdgcn_mfma_f32_16x16x32_bf16(a[1][kk], b, acc1, 0, 0, 0);
    }

    // fold into running best keys: key = (sv & ~1023) | (1023-code)
#pragma unroll
    for (int r = 0; r < 4; ++r) {
      float sv0 = acc0[r] + ct;
      bk[0][r] = fmaxf(bk[0][r], __uint_as_float((__float_as_uint(sv0) & 0xFFFFFC00u) | tr));
      float sv1 = acc1[r] + ct;
      bk[1][r] = fmaxf(bk[1][r], __uint_as_float((__float_as_uint(sv1) & 0xFFFFFC00u) | tr));
    }

    __syncthreads();   // drains prefetch (c+1 ready) + frees buf[cur] readers
  }

  // ---- reduce across 16 code-lanes, resolve per-row winner ----
#pragma unroll
  for (int mi = 0; mi < 2; ++mi)
#pragma unroll
    for (int r = 0; r < 4; ++r) {
      float v = bk[mi][r];
#pragma unroll
      for (int off = 1; off < 16; off <<= 1) v = fmaxf(v, __shfl_xor(v, off, 64));
      if (l15 == 0) cands[wc][wr * 32 + mi * 16 + lhi * 4 + r] = v;
    }
  __syncthreads();

  float sv = 0.0f;
  if (tid < ROWS) {
    float k = fmaxf(cands[0][tid], cands[1][tid]);
    unsigned ku = __float_as_uint(k);
    out_codes[row0 + tid] = 1023 - (int)(ku & 1023u);
    sv = __uint_as_float(ku & 0xFFFFFC00u);
  }
  red[tid] = x2a - 2.0f * sv;          // block partial: sum x^2 - 2*sum sv
  __syncthreads();
  for (int s = 128; s > 0; s >>= 1) {
    if (tid < s) red[tid] += red[tid + s];
    __syncthreads();
  }
  if (tid == 0) partials[blockIdx.x] = red[0];
}

// ---------------------------------------------------------------- gather (pure stream)
// One wave per row per iteration: 64 lanes x 16B = the full 1 KB row.
// codes prefetched 8-deep for MLP; ew is L2-resident (1 MB).
__global__ __launch_bounds__(256) void gather_kernel(const float* __restrict__ ew,
                                                     const int* __restrict__ codes,
                                                     float* __restrict__ qout) {
  const int wave = (blockIdx.x * 256 + threadIdx.x) >> 6;   // 0..8191
  const int lane = threadIdx.x & 63;
  int c[8];
#pragma unroll
  for (int i = 0; i < 8; ++i) c[i] = codes[wave + i * 8192];
#pragma unroll
  for (int i = 0; i < 8; ++i) {
    f32x4 v = *((const f32x4*)(ew + (size_t)c[i] * DIM) + lane);
    __builtin_nontemporal_store(v, ((f32x4*)(qout + (size_t)(wave + i * 8192) * DIM)) + lane);
  }
}

// ---------------------------------------------------------------- final loss
__global__ __launch_bounds__(256) void loss_kernel(const float* __restrict__ partials,
                                                   float* __restrict__ out_loss) {
  __shared__ double red[256];
  double a = 0.0;
  for (int i = threadIdx.x; i < 1024; i += 256) a += (double)partials[i];
  red[threadIdx.x] = a;
  __syncthreads();
  for (int s = 128; s > 0; s >>= 1) {
    if (threadIdx.x < s) red[threadIdx.x] += red[threadIdx.x + s];
    __syncthreads();
  }
  if (threadIdx.x == 0) out_loss[0] = (float)(1.25 * red[0] / 16777216.0);
}

// ---------------------------------------------------------------- launch
extern "C" void kernel_launch(void* const* d_in, const int* in_sizes, int n_in,
                              void* d_out, int out_size, void* d_ws, size_t ws_size,
                              hipStream_t stream) {
  const float* x  = (const float*)d_in[0];   // inputs [65536,256]
  const float* ew = (const float*)d_in[1];   // embed  [1024,256]
  float* out = (float*)d_out;

  char* ws = (char*)d_ws;
  short* ebf      = (short*)ws;                       // 512 KiB (pre-swizzled bf16)
  float* cneg     = (float*)(ws + 524288);            // 4 KiB
  float* partials = (float*)(ws + 528384);            // 4 KiB (1024 blocks)
  int*   codes    = (int*)(ws + 532480);              // 256 KiB

  prep_kernel<<<NCODES, 64, 0, stream>>>(ew, ebf, cneg);
  argmin_kernel<<<M_ROWS / ROWS, 256, 0, stream>>>(x, ebf, cneg, codes, partials);
  gather_kernel<<<M_ROWS / ROWS / 4, 256, 0, stream>>>(ew, codes, out);
  loss_kernel<<<1, 256, 0, stream>>>(partials, out + 16777216);
}

// Round 7
// 73.749 us; speedup vs baseline: 1.1243x; 1.0905x over previous
//
#include <hip/hip_runtime.h>
#include <hip/hip_bf16.h>

// Quantizer (VQ-VAE): inputs [32,2048,256] f32, embed [1024,256] f32.
// out = (quantized [32,2048,256] f32, latent_loss scalar f32) concatenated.
//
// Round-7 structure: NO LDS, NO BARRIERS in the hot kernel.
//   prep_kernel   : embed -> bf16 FRAGMENT-MAJOR pack (each MFMA B-fragment is a
//                   contiguous 1KB block: one coalesced wave-load) + cneg = -0.5||e||^2
//   argmin_kernel : 1 wave = 64 rows x ALL 1024 codes. A in regs (a[4][8]),
//                   B frags streamed from L2 with register ping-pong (1 chunk ahead),
//                   cneg folded into MFMA C-init, packed-key argmin, algebraic loss.
//   gather_kernel : q[r] = ew[codes[r]]  (FIXED round-6 bug: grid was 1/8 of rows;
//                   masked by |e|<=1/1024 << threshold)
//   loss_kernel   : final reduce -> 1.25 * [sum(x^2) - 2*sum(sv_win)] / (N*D)

#define DIM     256
#define M_ROWS  65536
#define NCODES  1024

using bf16x8  = __attribute__((ext_vector_type(8))) short;
using f32x4   = __attribute__((ext_vector_type(4))) float;
using short4v = __attribute__((ext_vector_type(4))) short;

__device__ inline short f2bf(float f) {
  union { __hip_bfloat16 h; short s; } u;
  u.h = __float2bfloat16(f);   // RTNE
  return u.s;
}

// ---------------------------------------------------------------- prep
// Fragment-major codebook: fragment (g, kk) covers codes [g*16, g*16+16) x
// k in [kk*32, kk*32+32). Lane l of a fragment holds code g*16+(l&15),
// k = kk*32 + (l>>4)*8 .. +8  (exactly the MFMA B-operand layout).
// Fragment f = g*8+kk stored contiguously: 64 lanes x 16 B = 1 KB.
__global__ __launch_bounds__(64) void prep_kernel(const float* __restrict__ ew,
                                                  short* __restrict__ ebf,
                                                  float* __restrict__ cneg) {
  const int c = blockIdx.x;
  const int t = threadIdx.x;            // handles k = 4t .. 4t+3
  f32x4 v = *((const f32x4*)(ew + (size_t)c * DIM) + t);
  short4v o;
  o.x = f2bf(v[0]); o.y = f2bf(v[1]); o.z = f2bf(v[2]); o.w = f2bf(v[3]);
  int g = c >> 4, l15v = c & 15;
  int kk = t >> 3, lhi = (t >> 1) & 3, half = t & 1;
  int lane = lhi * 16 + l15v;
  *(short4v*)(ebf + (size_t)((g * 8 + kk) * 64 + lane) * 8 + half * 4) = o;
  float ss = v[0] * v[0] + v[1] * v[1] + v[2] * v[2] + v[3] * v[3];
#pragma unroll
  for (int off = 32; off > 0; off >>= 1) ss += __shfl_xor(ss, off, 64);
  if (t == 0) cneg[c] = -0.5f * ss;
}

// ---------------------------------------------------------------- argmin
// Compute one 32-code chunk against this wave's 64 rows: 32 MFMA, C-init = cneg.
#define COMPUTE(B, CT, CBASE)                                                   \
  {                                                                             \
    _Pragma("unroll")                                                           \
    for (int n = 0; n < 2; ++n) {                                               \
      f32x4 acc[4];                                                             \
      _Pragma("unroll")                                                         \
      for (int mi = 0; mi < 4; ++mi)                                            \
        acc[mi] = f32x4{CT[n], CT[n], CT[n], CT[n]};                            \
      _Pragma("unroll")                                                         \
      for (int kk = 0; kk < 8; ++kk) {                                          \
        _Pragma("unroll")                                                       \
        for (int mi = 0; mi < 4; ++mi)                                          \
          acc[mi] = __builtin_amdgcn_mfma_f32_16x16x32_bf16(a[mi][kk],          \
                        B[n * 8 + kk], acc[mi], 0, 0, 0);                       \
      }                                                                         \
      unsigned tr = (unsigned)(1023 - ((CBASE) * 32 + n * 16 + l15));           \
      _Pragma("unroll")                                                         \
      for (int mi = 0; mi < 4; ++mi)                                            \
        _Pragma("unroll")                                                       \
        for (int r = 0; r < 4; ++r) {                                           \
          unsigned kb = (__float_as_uint(acc[mi][r]) & 0xFFFFFC00u) | tr;       \
          bk[mi][r] = fmaxf(bk[mi][r], __uint_as_float(kb));                    \
        }                                                                       \
    }                                                                           \
  }

__global__ __launch_bounds__(64, 1) void argmin_kernel(const float* __restrict__ x,
                                                       const short* __restrict__ ebf,
                                                       const float* __restrict__ cneg,
                                                       int* __restrict__ out_codes,
                                                       float* __restrict__ partials) {
  const int lane = threadIdx.x;
  const int l15  = lane & 15;
  const int lhi  = lane >> 4;            // 0..3
  const int row0 = blockIdx.x * 64;

  // ---- X -> registers (bf16 frags), x2a = sum of squares ----
  float x2a = 0.0f;
  bf16x8 a[4][8];
#pragma unroll
  for (int mi = 0; mi < 4; ++mi) {
    const float* xr = x + (size_t)(row0 + mi * 16 + l15) * DIM;
#pragma unroll
    for (int kk = 0; kk < 8; ++kk) {
      f32x4 v0 = *(const f32x4*)(xr + kk * 32 + lhi * 8);
      f32x4 v1 = *(const f32x4*)(xr + kk * 32 + lhi * 8 + 4);
      x2a += v0[0] * v0[0] + v0[1] * v0[1] + v0[2] * v0[2] + v0[3] * v0[3]
           + v1[0] * v1[0] + v1[1] * v1[1] + v1[2] * v1[2] + v1[3] * v1[3];
      union { bf16x8 v; short s[8]; } pk;
      pk.s[0] = f2bf(v0[0]); pk.s[1] = f2bf(v0[1]); pk.s[2] = f2bf(v0[2]); pk.s[3] = f2bf(v0[3]);
      pk.s[4] = f2bf(v1[0]); pk.s[5] = f2bf(v1[1]); pk.s[6] = f2bf(v1[2]); pk.s[7] = f2bf(v1[3]);
      a[mi][kk] = pk.v;
    }
  }

  float bk[4][4];
#pragma unroll
  for (int i = 0; i < 4; ++i)
#pragma unroll
    for (int r = 0; r < 4; ++r) bk[i][r] = -__builtin_inff();

  // ---- B register ping-pong: 16 frags (1 chunk of 32 codes) ahead ----
  const bf16x8* bf = (const bf16x8*)ebf;   // frag f, lane l -> bf[f*64 + l]
  bf16x8 bA[16], bB[16];
  float  ctA[2], ctB[2];
#pragma unroll
  for (int f = 0; f < 16; ++f) bA[f] = bf[f * 64 + lane];
  ctA[0] = cneg[l15]; ctA[1] = cneg[16 + l15];

  for (int c = 0; c < 32; c += 2) {
    // prefetch chunk c+1 while computing c
#pragma unroll
    for (int f = 0; f < 16; ++f) bB[f] = bf[((c + 1) * 16 + f) * 64 + lane];
    ctB[0] = cneg[(c + 1) * 32 + l15]; ctB[1] = cneg[(c + 1) * 32 + 16 + l15];
    COMPUTE(bA, ctA, c);
    // prefetch chunk c+2 while computing c+1
    if (c + 2 < 32) {
#pragma unroll
      for (int f = 0; f < 16; ++f) bA[f] = bf[((c + 2) * 16 + f) * 64 + lane];
      ctA[0] = cneg[(c + 2) * 32 + l15]; ctA[1] = cneg[(c + 2) * 32 + 16 + l15];
    }
    COMPUTE(bB, ctB, c + 1);
  }

  // ---- argmin resolve: reduce packed keys over the 16 code-lanes ----
#pragma unroll
  for (int mi = 0; mi < 4; ++mi)
#pragma unroll
    for (int r = 0; r < 4; ++r) {
      float v = bk[mi][r];
#pragma unroll
      for (int off = 1; off < 16; off <<= 1) v = fmaxf(v, __shfl_xor(v, off, 64));
      bk[mi][r] = v;
    }

  float svtot = 0.0f;
  if (l15 == 0) {                        // lanes 0,16,32,48: rows mi*16 + lhi*4 + r
#pragma unroll
    for (int mi = 0; mi < 4; ++mi)
#pragma unroll
      for (int r = 0; r < 4; ++r) {
        unsigned ku = __float_as_uint(bk[mi][r]);
        out_codes[row0 + mi * 16 + lhi * 4 + r] = 1023 - (int)(ku & 1023u);
        svtot += __uint_as_float(ku & 0xFFFFFC00u);
      }
  }
  float red = x2a - 2.0f * svtot;        // block partial: sum x^2 - 2*sum sv
#pragma unroll
  for (int off = 1; off < 64; off <<= 1) red += __shfl_xor(red, off, 64);
  if (lane == 0) partials[blockIdx.x] = red;
}

// ---------------------------------------------------------------- gather (pure stream)
// One wave per 8 consecutive rows; each row = 1 KB contiguous (64 lanes x 16 B).
// FIX vs round 6: grid 2048 (8192 waves x 8 rows = 65536 rows, full coverage).
__global__ __launch_bounds__(256) void gather_kernel(const float* __restrict__ ew,
                                                     const int* __restrict__ codes,
                                                     float* __restrict__ qout) {
  const int w    = (blockIdx.x * 256 + threadIdx.x) >> 6;   // 0..8191
  const int lane = threadIdx.x & 63;
  const int base = w * 8;
  int c[8];
#pragma unroll
  for (int i = 0; i < 8; ++i) c[i] = codes[base + i];
#pragma unroll
  for (int i = 0; i < 8; ++i) {
    f32x4 v = *((const f32x4*)(ew + (size_t)c[i] * DIM) + lane);
    __builtin_nontemporal_store(v, ((f32x4*)(qout + (size_t)(base + i) * DIM)) + lane);
  }
}

// ---------------------------------------------------------------- final loss
__global__ __launch_bounds__(256) void loss_kernel(const float* __restrict__ partials,
                                                   float* __restrict__ out_loss) {
  __shared__ double red[256];
  double a = 0.0;
  for (int i = threadIdx.x; i < 1024; i += 256) a += (double)partials[i];
  red[threadIdx.x] = a;
  __syncthreads();
  for (int s = 128; s > 0; s >>= 1) {
    if (threadIdx.x < s) red[threadIdx.x] += red[threadIdx.x + s];
    __syncthreads();
  }
  if (threadIdx.x == 0) out_loss[0] = (float)(1.25 * red[0] / 16777216.0);
}

// ---------------------------------------------------------------- launch
extern "C" void kernel_launch(void* const* d_in, const int* in_sizes, int n_in,
                              void* d_out, int out_size, void* d_ws, size_t ws_size,
                              hipStream_t stream) {
  const float* x  = (const float*)d_in[0];   // inputs [65536,256]
  const float* ew = (const float*)d_in[1];   // embed  [1024,256]
  float* out = (float*)d_out;

  char* ws = (char*)d_ws;
  short* ebf      = (short*)ws;                       // 512 KiB (fragment-major bf16)
  float* cneg     = (float*)(ws + 524288);            // 4 KiB
  float* partials = (float*)(ws + 528384);            // 4 KiB (1024 waves)
  int*   codes    = (int*)(ws + 532480);              // 256 KiB

  prep_kernel<<<NCODES, 64, 0, stream>>>(ew, ebf, cneg);
  argmin_kernel<<<M_ROWS / 64, 64, 0, stream>>>(x, ebf, cneg, codes, partials);
  gather_kernel<<<2048, 256, 0, stream>>>(ew, codes, out);
  loss_kernel<<<1, 256, 0, stream>>>(partials, out + 16777216);
}

// Round 8
// 71.091 us; speedup vs baseline: 1.1664x; 1.0374x over previous
//
#include <hip/hip_runtime.h>
#include <hip/hip_bf16.h>

// Quantizer (VQ-VAE): inputs [32,2048,256] f32, embed [1024,256] f32.
// out = (quantized [32,2048,256] f32, latent_loss scalar f32) concatenated.
//
// Round-8: round-7 structure (no LDS / no barriers, fragment-major L2-resident
// codebook, register ping-pong) with the REGISTER SPILL fixed: B ping-pong
// buffers halved to 8 frags (16 codes) so total VGPR ~245 < 256 arch cap.
// Round-7 spilled (VGPR=256 cap hit, WRITE_SIZE 24.6 MB of scratch traffic).
//
//   prep_kernel   : embed -> bf16 FRAGMENT-MAJOR pack + cneg = -0.5||e||^2
//   argmin_kernel : 1 wave = 64 rows x ALL 1024 codes; A in regs a[4][8];
//                   B streamed from L2, ping-pong 16 codes ahead;
//                   cneg in MFMA C-init; packed-key argmin; algebraic loss.
//   gather_kernel : q[r] = ew[codes[r]] (1 KB contiguous nt-store per row)
//   loss_kernel   : final reduce -> 1.25 * [sum(x^2) - 2*sum(sv_win)] / (N*D)

#define DIM     256
#define M_ROWS  65536
#define NCODES  1024

using bf16x8  = __attribute__((ext_vector_type(8))) short;
using f32x4   = __attribute__((ext_vector_type(4))) float;
using short4v = __attribute__((ext_vector_type(4))) short;

__device__ inline short f2bf(float f) {
  union { __hip_bfloat16 h; short s; } u;
  u.h = __float2bfloat16(f);   // RTNE
  return u.s;
}

// ---------------------------------------------------------------- prep
// Fragment-major codebook: fragment (g, kk) covers codes [g*16, g*16+16) x
// k in [kk*32, kk*32+32). Lane l holds code g*16+(l&15), k = kk*32+(l>>4)*8..+8
// (exactly the MFMA B-operand layout). Fragment f = g*8+kk is 1 KB contiguous.
__global__ __launch_bounds__(64) void prep_kernel(const float* __restrict__ ew,
                                                  short* __restrict__ ebf,
                                                  float* __restrict__ cneg) {
  const int c = blockIdx.x;
  const int t = threadIdx.x;            // handles k = 4t .. 4t+3
  f32x4 v = *((const f32x4*)(ew + (size_t)c * DIM) + t);
  short4v o;
  o.x = f2bf(v[0]); o.y = f2bf(v[1]); o.z = f2bf(v[2]); o.w = f2bf(v[3]);
  int g = c >> 4, l15v = c & 15;
  int kk = t >> 3, lhi = (t >> 1) & 3, half = t & 1;
  int lane = lhi * 16 + l15v;
  *(short4v*)(ebf + (size_t)((g * 8 + kk) * 64 + lane) * 8 + half * 4) = o;
  float ss = v[0] * v[0] + v[1] * v[1] + v[2] * v[2] + v[3] * v[3];
#pragma unroll
  for (int off = 32; off > 0; off >>= 1) ss += __shfl_xor(ss, off, 64);
  if (t == 0) cneg[c] = -0.5f * ss;
}

// ---------------------------------------------------------------- argmin
// One 16-code group: 32 MFMA with C-init = cneg, then pack+max 16 elements.
#define COMPUTE16(B, CT, G)                                                     \
  {                                                                             \
    f32x4 acc[4];                                                               \
    _Pragma("unroll")                                                           \
    for (int mi = 0; mi < 4; ++mi) acc[mi] = f32x4{CT, CT, CT, CT};             \
    _Pragma("unroll")                                                           \
    for (int kk = 0; kk < 8; ++kk) {                                            \
      _Pragma("unroll")                                                         \
      for (int mi = 0; mi < 4; ++mi)                                            \
        acc[mi] = __builtin_amdgcn_mfma_f32_16x16x32_bf16(a[mi][kk], B[kk],     \
                                                          acc[mi], 0, 0, 0);    \
    }                                                                           \
    unsigned tr = (unsigned)(1023 - ((G) * 16 + l15));                          \
    _Pragma("unroll")                                                           \
    for (int mi = 0; mi < 4; ++mi)                                              \
      _Pragma("unroll")                                                         \
      for (int r = 0; r < 4; ++r) {                                             \
        unsigned kb = (__float_as_uint(acc[mi][r]) & 0xFFFFFC00u) | tr;         \
        bk[mi][r] = fmaxf(bk[mi][r], __uint_as_float(kb));                      \
      }                                                                         \
  }

__global__ __launch_bounds__(64, 1) void argmin_kernel(const float* __restrict__ x,
                                                       const short* __restrict__ ebf,
                                                       const float* __restrict__ cneg,
                                                       int* __restrict__ out_codes,
                                                       float* __restrict__ partials) {
  const int lane = threadIdx.x;
  const int l15  = lane & 15;
  const int lhi  = lane >> 4;            // 0..3
  const int row0 = blockIdx.x * 64;

  // ---- X -> registers (bf16 frags), x2a = sum of squares ----
  float x2a = 0.0f;
  bf16x8 a[4][8];
#pragma unroll
  for (int mi = 0; mi < 4; ++mi) {
    const float* xr = x + (size_t)(row0 + mi * 16 + l15) * DIM;
#pragma unroll
    for (int kk = 0; kk < 8; ++kk) {
      f32x4 v0 = *(const f32x4*)(xr + kk * 32 + lhi * 8);
      f32x4 v1 = *(const f32x4*)(xr + kk * 32 + lhi * 8 + 4);
      x2a += v0[0] * v0[0] + v0[1] * v0[1] + v0[2] * v0[2] + v0[3] * v0[3]
           + v1[0] * v1[0] + v1[1] * v1[1] + v1[2] * v1[2] + v1[3] * v1[3];
      union { bf16x8 v; short s[8]; } pk;
      pk.s[0] = f2bf(v0[0]); pk.s[1] = f2bf(v0[1]); pk.s[2] = f2bf(v0[2]); pk.s[3] = f2bf(v0[3]);
      pk.s[4] = f2bf(v1[0]); pk.s[5] = f2bf(v1[1]); pk.s[6] = f2bf(v1[2]); pk.s[7] = f2bf(v1[3]);
      a[mi][kk] = pk.v;
    }
  }

  float bk[4][4];
#pragma unroll
  for (int i = 0; i < 4; ++i)
#pragma unroll
    for (int r = 0; r < 4; ++r) bk[i][r] = -__builtin_inff();

  // ---- B register ping-pong: 8 frags (one 16-code group) ahead ----
  const bf16x8* bfr = (const bf16x8*)ebf;  // frag f, lane l -> bfr[f*64 + l]
  bf16x8 bA[8], bB[8];
  float  ctA, ctB;
#pragma unroll
  for (int f = 0; f < 8; ++f) bA[f] = bfr[f * 64 + lane];
  ctA = cneg[l15];

  for (int g = 0; g < 64; g += 2) {
    // prefetch group g+1 while computing g
#pragma unroll
    for (int f = 0; f < 8; ++f) bB[f] = bfr[((g + 1) * 8 + f) * 64 + lane];
    ctB = cneg[(g + 1) * 16 + l15];
    COMPUTE16(bA, ctA, g);
    // prefetch group g+2 while computing g+1
    if (g + 2 < 64) {
#pragma unroll
      for (int f = 0; f < 8; ++f) bA[f] = bfr[((g + 2) * 8 + f) * 64 + lane];
      ctA = cneg[(g + 2) * 16 + l15];
    }
    COMPUTE16(bB, ctB, g + 1);
  }

  // ---- argmin resolve: reduce packed keys over the 16 code-lanes ----
#pragma unroll
  for (int mi = 0; mi < 4; ++mi)
#pragma unroll
    for (int r = 0; r < 4; ++r) {
      float v = bk[mi][r];
#pragma unroll
      for (int off = 1; off < 16; off <<= 1) v = fmaxf(v, __shfl_xor(v, off, 64));
      bk[mi][r] = v;
    }

  float svtot = 0.0f;
  if (l15 == 0) {                        // lanes 0,16,32,48: rows mi*16 + lhi*4 + r
#pragma unroll
    for (int mi = 0; mi < 4; ++mi)
#pragma unroll
      for (int r = 0; r < 4; ++r) {
        unsigned ku = __float_as_uint(bk[mi][r]);
        out_codes[row0 + mi * 16 + lhi * 4 + r] = 1023 - (int)(ku & 1023u);
        svtot += __uint_as_float(ku & 0xFFFFFC00u);
      }
  }
  float red = x2a - 2.0f * svtot;        // block partial: sum x^2 - 2*sum sv
#pragma unroll
  for (int off = 1; off < 64; off <<= 1) red += __shfl_xor(red, off, 64);
  if (lane == 0) partials[blockIdx.x] = red;
}

// ---------------------------------------------------------------- gather (pure stream)
// One wave per 8 consecutive rows; each row = 1 KB contiguous (64 lanes x 16 B).
__global__ __launch_bounds__(256) void gather_kernel(const float* __restrict__ ew,
                                                     const int* __restrict__ codes,
                                                     float* __restrict__ qout) {
  const int w    = (blockIdx.x * 256 + threadIdx.x) >> 6;   // 0..8191
  const int lane = threadIdx.x & 63;
  const int base = w * 8;
  int c[8];
#pragma unroll
  for (int i = 0; i < 8; ++i) c[i] = codes[base + i];
#pragma unroll
  for (int i = 0; i < 8; ++i) {
    f32x4 v = *((const f32x4*)(ew + (size_t)c[i] * DIM) + lane);
    __builtin_nontemporal_store(v, ((f32x4*)(qout + (size_t)(base + i) * DIM)) + lane);
  }
}

// ---------------------------------------------------------------- final loss
__global__ __launch_bounds__(256) void loss_kernel(const float* __restrict__ partials,
                                                   float* __restrict__ out_loss) {
  __shared__ double red[256];
  double a = 0.0;
  for (int i = threadIdx.x; i < 1024; i += 256) a += (double)partials[i];
  red[threadIdx.x] = a;
  __syncthreads();
  for (int s = 128; s > 0; s >>= 1) {
    if (threadIdx.x < s) red[threadIdx.x] += red[threadIdx.x + s];
    __syncthreads();
  }
  if (threadIdx.x == 0) out_loss[0] = (float)(1.25 * red[0] / 16777216.0);
}

// ---------------------------------------------------------------- launch
extern "C" void kernel_launch(void* const* d_in, const int* in_sizes, int n_in,
                              void* d_out, int out_size, void* d_ws, size_t ws_size,
                              hipStream_t stream) {
  const float* x  = (const float*)d_in[0];   // inputs [65536,256]
  const float* ew = (const float*)d_in[1];   // embed  [1024,256]
  float* out = (float*)d_out;

  char* ws = (char*)d_ws;
  short* ebf      = (short*)ws;                       // 512 KiB (fragment-major bf16)
  float* cneg     = (float*)(ws + 524288);            // 4 KiB
  float* partials = (float*)(ws + 528384);            // 4 KiB (1024 waves)
  int*   codes    = (int*)(ws + 532480);              // 256 KiB

  prep_kernel<<<NCODES, 64, 0, stream>>>(ew, ebf, cneg);
  argmin_kernel<<<M_ROWS / 64, 64, 0, stream>>>(x, ebf, cneg, codes, partials);
  gather_kernel<<<2048, 256, 0, stream>>>(ew, codes, out);
  loss_kernel<<<1, 256, 0, stream>>>(partials, out + 16777216);
}